// Round 10
// baseline (32753.366 us; speedup 1.0000x reference)
//
#include <hip/hip_runtime.h>
#include <hip/hip_bf16.h>
#include <math.h>

typedef unsigned short u16;
typedef short short8v __attribute__((ext_vector_type(8)));
typedef float f32x4 __attribute__((ext_vector_type(4)));

#define TT 512
#define BB 128
#define IND 259
#define KPWF 384

// k_gemm LDS: per buffer: A_hi[128][144] A_lo B_hi[128][144] B_lo = 4*18432 = 73728; x2 = 147456
#define APL 18432
#define GBUFB 73728
#define LDS_G 147456
// head core (R9-proven, M=64 BK=64): 73728
#define LDS_H 73728

__device__ __forceinline__ u16 f2bf(float x) {
    __hip_bfloat16 h = __float2bfloat16(x);
    return *reinterpret_cast<u16*>(&h);
}
__device__ __forceinline__ float bf2f(u16 u) {
    unsigned v = ((unsigned)u) << 16;
    return __uint_as_float(v);
}
__device__ __forceinline__ void splitbf(float x, u16& hi, u16& lo) {
    hi = f2bf(x);
    lo = f2bf(x - bf2f(hi));
}
__device__ __forceinline__ float sigm(float x) { return 1.f / (1.f + expf(-x)); }

// ---------------- small prep kernels ----------------
__global__ __launch_bounds__(256) void k_zero(float* __restrict__ p, int n) {
    int i = blockIdx.x * 256 + threadIdx.x;
    int stride = gridDim.x * 256;
    for (; i < n; i += stride) p[i] = 0.f;
}

__global__ __launch_bounds__(256) void k_fold(const float* __restrict__ embW,
                                              const float* __restrict__ W0,
                                              float* __restrict__ WF) {
    int j = blockIdx.x * 256 + threadIdx.x;
    int i = blockIdx.y;
    float acc = 0.f;
    for (int e = 0; e < 512; ++e)
        acc += embW[i * 512 + e] * W0[(size_t)e * 4096 + j];
    WF[(size_t)i * 4096 + j] = acc;
}

__global__ __launch_bounds__(256) void k_S(const float* __restrict__ W0, float* __restrict__ S) {
    int j = blockIdx.x * 256 + threadIdx.x;
    float acc = 0.f;
    for (int r = 0; r < 128; ++r)
        acc += W0[(size_t)(512 + r) * 4096 + j];
    S[j] = acc;
}

__global__ __launch_bounds__(256) void k_sgn(const float* __restrict__ inp, float* __restrict__ sgn) {
    int i = blockIdx.x * 256 + threadIdx.x;
    float f0 = inp[(size_t)i * IND + 256];
    float f1 = inp[(size_t)i * IND + 257];
    sgn[i] = (f0 == 1.0f && f1 == 0.0f) ? 1.0f : -1.0f;
}

// Transpose + bf16 hi/lo split (+ optional gate-permute of columns).
// perm: col' = hs*64 + g*16 + c  <->  j = g*1024 + hs*16 + c
__global__ __launch_bounds__(256) void k_split(const float* __restrict__ src, int srcStride,
                                               int K, int Kpad, int perm,
                                               u16* __restrict__ hi, u16* __restrict__ lo) {
    int col = blockIdx.y;
    int k = blockIdx.x * 256 + threadIdx.x;
    if (k >= Kpad) return;
    int j = col;
    if (perm) {
        int c = col & 15, g = (col >> 4) & 3, hs = col >> 6;
        j = g * 1024 + hs * 16 + c;
    }
    float v = (k < K) ? src[(size_t)k * srcStride + j] : 0.f;
    u16 h, l; splitbf(v, h, l);
    hi[(size_t)col * Kpad + k] = h;
    lo[(size_t)col * Kpad + k] = l;
}

// ================= 128x128 split-bf16 MFMA core (BK=64, 4 waves 2x2, 64x64/wave) =================
template<int AMODE>
__device__ __forceinline__ void gemm128(
    char* smem, int tid,
    const u16* Ah, const u16* Al, int lda,   // AMODE0: bf16 hi/lo A (pre-offset incl. K-slice)
    const float* Af, int kmax,               // AMODE1: fp32 A, lda=IND, guard k<kmax
    const u16* Bh, const u16* Bl, int ldb,   // pre-offset (col-block, K-slice)
    int ntiles,
    f32x4 (&acc)[4][4])
{
    const int lane = tid & 63, wid = tid >> 6;
    const int wrg = wid >> 1, wcg = wid & 1;
    const int rlo = lane & 15, khi = lane >> 4;

    const int srow = tid >> 1;   // 0..127 (A row == B col)
    const int sh   = tid & 1;    // which 64B half of the 128B row

    uint4 rah[4], ral[4], rbh[4], rbl[4];
    float rf[32];

    auto LOADF = [&](int tile) {
        if constexpr (AMODE == 0) {
            const u16* pa = Ah + (size_t)srow * lda + tile * 64 + sh * 32;
            const u16* pl = Al + (size_t)srow * lda + tile * 64 + sh * 32;
            #pragma unroll
            for (int j = 0; j < 4; ++j) {
                rah[j] = *(const uint4*)(pa + j * 8);
                ral[j] = *(const uint4*)(pl + j * 8);
            }
        } else {
            const float* sa = Af + (size_t)srow * lda;
            int k0 = tile * 64 + sh * 32;
            #pragma unroll
            for (int j = 0; j < 32; ++j) rf[j] = (k0 + j < kmax) ? sa[k0 + j] : 0.f;
        }
        const u16* pb = Bh + (size_t)srow * ldb + tile * 64 + sh * 32;
        const u16* pq = Bl + (size_t)srow * ldb + tile * 64 + sh * 32;
        #pragma unroll
        for (int j = 0; j < 4; ++j) {
            rbh[j] = *(const uint4*)(pb + j * 8);
            rbl[j] = *(const uint4*)(pq + j * 8);
        }
    };
    auto WRITEF = [&](int tile) {
        char* buf = smem + (tile & 1) * GBUFB;
        char* da = buf + srow * 144 + sh * 64;
        if constexpr (AMODE == 0) {
            #pragma unroll
            for (int j = 0; j < 4; ++j) {
                *(uint4*)(da + j * 16) = rah[j];
                *(uint4*)(da + APL + j * 16) = ral[j];
            }
        } else {
            alignas(16) u16 hb[32], lb[32];
            #pragma unroll
            for (int j = 0; j < 32; ++j) splitbf(rf[j], hb[j], lb[j]);
            #pragma unroll
            for (int j = 0; j < 4; ++j) {
                *(uint4*)(da + j * 16) = *(const uint4*)(hb + j * 8);
                *(uint4*)(da + APL + j * 16) = *(const uint4*)(lb + j * 8);
            }
        }
        char* db = buf + 2 * APL + srow * 144 + sh * 64;
        #pragma unroll
        for (int j = 0; j < 4; ++j) {
            *(uint4*)(db + j * 16) = rbh[j];
            *(uint4*)(db + APL + j * 16) = rbl[j];
        }
    };
    auto COMPUTEF = [&](int kt) {
        const char* buf = smem + (kt & 1) * GBUFB;
        #pragma unroll
        for (int ks = 0; ks < 2; ++ks) {
            short8v ah[4], al[4];
            #pragma unroll
            for (int rfi = 0; rfi < 4; ++rfi) {
                int row = wrg * 64 + rfi * 16 + rlo;
                const char* p = buf + row * 144 + ks * 64 + khi * 16;
                ah[rfi] = *(const short8v*)p;
                al[rfi] = *(const short8v*)(p + APL);
            }
            #pragma unroll
            for (int cfi = 0; cfi < 4; ++cfi) {
                int col = wcg * 64 + cfi * 16 + rlo;
                const char* q = buf + 2 * APL + col * 144 + ks * 64 + khi * 16;
                short8v bh = *(const short8v*)q;
                short8v bl = *(const short8v*)(q + APL);
                #pragma unroll
                for (int rfi = 0; rfi < 4; ++rfi) {
                    acc[rfi][cfi] = __builtin_amdgcn_mfma_f32_16x16x32_bf16(ah[rfi], bh, acc[rfi][cfi], 0, 0, 0);
                    acc[rfi][cfi] = __builtin_amdgcn_mfma_f32_16x16x32_bf16(ah[rfi], bl, acc[rfi][cfi], 0, 0, 0);
                    acc[rfi][cfi] = __builtin_amdgcn_mfma_f32_16x16x32_bf16(al[rfi], bh, acc[rfi][cfi], 0, 0, 0);
                }
            }
        }
    };

    LOADF(0); WRITEF(0); __syncthreads();
    for (int kt = 0; kt < ntiles; ++kt) {
        if (kt + 1 < ntiles) LOADF(kt + 1);
        COMPUTEF(kt);
        if (kt + 1 < ntiles) WRITEF(kt + 1);
        __syncthreads();
    }
}

__device__ __forceinline__ void store_acc128(float* __restrict__ out, int col0, int tid,
                                             f32x4 (&acc)[4][4]) {
    const int lane = tid & 63, wid = tid >> 6;
    const int wrg = wid >> 1, wcg = wid & 1;
    const int rlo = lane & 15, khi = lane >> 4;
    #pragma unroll
    for (int rfi = 0; rfi < 4; ++rfi)
        #pragma unroll
        for (int cfi = 0; cfi < 4; ++cfi)
            #pragma unroll
            for (int r = 0; r < 4; ++r)
                out[(size_t)(wrg*64 + rfi*16 + khi*4 + r) * 4096 + col0 + wcg*64 + cfi*16 + rlo] = acc[rfi][cfi][r];
}

// ---------------- launch A: GEMM partials (224 wgs) ----------------
struct GArgs {
    const float* inp;
    const u16 *WFh, *WFl, *W0h, *W0l, *W1h, *W1l;
    const u16 *h0h0, *h0l0, *h0h1, *h0l1;
    const u16 *ringh, *ringl;
    float *P0, *P1, *Zin;
    int R, t;
};

__global__ __launch_bounds__(256) void k_gemm(GArgs a) {
    extern __shared__ char smem[];
    const int bid = blockIdx.x, tid = threadIdx.x;
    const int t = a.t;
    f32x4 acc[4][4];
    #pragma unroll
    for (int i = 0; i < 4; ++i)
        #pragma unroll
        for (int j = 0; j < 4; ++j) acc[i][j] = (f32x4)0.f;

    if (bid < 64) {
        // cell0(t): partial = h0(t-1)[Kslice] @ W0[Kslice, 128cols]
        if (t < 0 || t >= TT) return;
        const int cb = bid >> 1, s = bid & 1;
        const u16* Ah = (((t - 1) & 1) ? a.h0h1 : a.h0h0) + s * 512;
        const u16* Al = (((t - 1) & 1) ? a.h0l1 : a.h0l0) + s * 512;
        gemm128<0>(smem, tid, Ah, Al, 1024, nullptr, 0,
                   a.W0h + (size_t)(cb * 128) * 1024 + s * 512,
                   a.W0l + (size_t)(cb * 128) * 1024 + s * 512, 1024, 8, acc);
        store_acc128(a.P0 + (size_t)s * BB * 4096, cb * 128, tid, acc);
    } else if (bid < 192) {
        // cell1(t-1): slices 0,1 from h0(tau); 2,3 from h1(tau-1)
        const int tau = t - 1;
        if (tau < 0 || tau >= TT) return;
        const int q = bid - 64, cb = q >> 2, s = q & 3;
        const u16 *Ah, *Al;
        if (s < 2) {
            Ah = (((tau & 1) ? a.h0h1 : a.h0h0)) + s * 512;
            Al = (((tau & 1) ? a.h0l1 : a.h0l0)) + s * 512;
        } else {
            int slot = (tau - 1 + a.R) % a.R;
            Ah = a.ringh + (size_t)slot * BB * 1024 + (s - 2) * 512;
            Al = a.ringl + (size_t)slot * BB * 1024 + (s - 2) * 512;
        }
        gemm128<0>(smem, tid, Ah, Al, 1024, nullptr, 0,
                   a.W1h + (size_t)(cb * 128) * 2048 + s * 512,
                   a.W1l + (size_t)(cb * 128) * 2048 + s * 512, 2048, 8, acc);
        store_acc128(a.P1 + (size_t)s * BB * 4096, cb * 128, tid, acc);
    } else {
        // Zin(t+1) = inp[t+1] @ WF (K=384 padded, guard 259)
        const int tz = t + 1;
        if (tz < 0 || tz >= TT) return;
        const int cb = bid - 192;
        gemm128<1>(smem, tid, nullptr, nullptr, IND,
                   a.inp + (size_t)tz * BB * IND, IND,
                   a.WFh + (size_t)(cb * 128) * KPWF,
                   a.WFl + (size_t)(cb * 128) * KPWF, KPWF, 6, acc);
        store_acc128(a.Zin + (size_t)(tz & 1) * BB * 4096, cb * 128, tid, acc);
    }
}

// ---------------- launch B: combine + gates (64 wgs) ----------------
struct TArgs {
    const float *P0, *P1, *Zin, *Sv, *SG, *b0, *b1;
    float *c0, *c1;
    u16 *h0h0, *h0l0, *h0h1, *h0l1, *ringh, *ringl;
    int R, t;
};

template<int NS, bool CELL0>
__device__ __forceinline__ void gate_work(
    const float* __restrict__ Pb,      // pre-offset: + row*4096 + hs*64
    const float* __restrict__ zin,     // pre-offset (CELL0 only)
    float sg, const float* __restrict__ Sv,
    const float* __restrict__ bias,
    float* __restrict__ cst, u16* __restrict__ oh, u16* __restrict__ ol,
    int row, int hs)
{
    float z[4][16];
    #pragma unroll
    for (int g = 0; g < 4; ++g) {
        #pragma unroll
        for (int c4 = 0; c4 < 4; ++c4) {
            float4 v = make_float4(0.f, 0.f, 0.f, 0.f);
            #pragma unroll
            for (int s = 0; s < NS; ++s) {
                float4 p = *(const float4*)(Pb + (size_t)s * BB * 4096 + g * 16 + c4 * 4);
                v.x += p.x; v.y += p.y; v.z += p.z; v.w += p.w;
            }
            if (CELL0) {
                float4 p = *(const float4*)(zin + g * 16 + c4 * 4);
                v.x += p.x; v.y += p.y; v.z += p.z; v.w += p.w;
                float4 sv = *(const float4*)(Sv + g * 1024 + hs * 16 + c4 * 4);
                v.x += sg * sv.x; v.y += sg * sv.y; v.z += sg * sv.z; v.w += sg * sv.w;
            }
            float4 bv = *(const float4*)(bias + g * 1024 + hs * 16 + c4 * 4);
            v.x += bv.x; v.y += bv.y; v.z += bv.z; v.w += bv.w;
            z[g][c4*4+0] = v.x; z[g][c4*4+1] = v.y; z[g][c4*4+2] = v.z; z[g][c4*4+3] = v.w;
        }
    }
    alignas(16) u16 hh[16], hl[16];
    float* cp = cst + (size_t)row * 1024 + hs * 16;
    #pragma unroll
    for (int c4 = 0; c4 < 4; ++c4) {
        float4 cv = *(const float4*)(cp + c4 * 4);
        float cc[4] = {cv.x, cv.y, cv.z, cv.w};
        #pragma unroll
        for (int e = 0; e < 4; ++e) {
            int c = c4 * 4 + e;
            float F = sigm(z[0][c]);
            float I = sigm(z[1][c]);
            float O = sigm(z[2][c]);
            float G = tanhf(z[3][c]);
            float cn = F * cc[e] + I * G;
            cc[e] = cn;
            float h = O * tanhf(cn);
            splitbf(h, hh[c], hl[c]);
        }
        *(float4*)(cp + c4 * 4) = make_float4(cc[0], cc[1], cc[2], cc[3]);
    }
    u16* ph = oh + (size_t)row * 1024 + hs * 16;
    u16* pl = ol + (size_t)row * 1024 + hs * 16;
    *(uint4*)(ph) = *(const uint4*)(hh);
    *(uint4*)(ph + 8) = *(const uint4*)(hh + 8);
    *(uint4*)(pl) = *(const uint4*)(hl);
    *(uint4*)(pl + 8) = *(const uint4*)(hl + 8);
}

__global__ __launch_bounds__(256) void k_gate(TArgs a) {
    const int bid = blockIdx.x, tid = threadIdx.x;
    if (bid < 32) {
        const int t = a.t;
        if (t < 0 || t >= TT) return;
        int q = bid * 256 + tid;          // 8192 = 128 rows x 64 hs
        int row = q >> 6, hs = q & 63;
        const float* Pb = a.P0 + (size_t)row * 4096 + hs * 64;
        const float* zin = a.Zin + (size_t)(t & 1) * BB * 4096 + (size_t)row * 4096 + hs * 64;
        float sg = a.SG[(size_t)t * BB + row];
        u16* oh = (t & 1) ? a.h0h1 : a.h0h0;
        u16* ol = (t & 1) ? a.h0l1 : a.h0l0;
        gate_work<2, true>(Pb, zin, sg, a.Sv, a.b0, a.c0, oh, ol, row, hs);
    } else {
        const int tau = a.t - 1;
        if (tau < 0 || tau >= TT) return;
        int q = (bid - 32) * 256 + tid;
        int row = q >> 6, hs = q & 63;
        const float* Pb = a.P1 + (size_t)row * 4096 + hs * 64;
        int slot = tau % a.R;
        u16* oh = a.ringh + (size_t)slot * BB * 1024;
        u16* ol = a.ringl + (size_t)slot * BB * 1024;
        gate_work<4, false>(Pb, nullptr, 0.f, nullptr, a.b1, a.c1, oh, ol, row, hs);
    }
}

// ================= R9-proven head core (M=64, BK=64) =================
template<int NC, int AMODE>
__device__ __forceinline__ void gemm_core(
    char* smem, int tid,
    const u16* Ah0, const u16* Al0,
    const u16* Ah1, const u16* Al1,
    int phsw, const float* Af,
    const u16* Bh, const u16* Bl, int ldb,
    int bmode, int bhalf, int nkt,
    f32x4 (&acc)[2][NC/32])
{
    constexpr int ROWB = 144;
    constexpr int APL2 = 64 * ROWB;
    constexpr int BPL  = NC * ROWB;
    constexpr int BUFB = 2 * APL2 + 2 * BPL;
    const int lane = tid & 63, wid = tid >> 6;
    const int wrg = wid >> 1, wcg = wid & 1;
    const int rlo = lane & 15, khi = lane >> 4;
    const int srow = tid >> 2;
    const int skE  = (tid & 3) * 16;
    int bcol, bplane, bq;
    if (NC == 64) { bcol = tid >> 2; int bs = tid & 3; bplane = bs >> 1; bq = bs & 1; }
    else          { bcol = tid >> 3; int bs = tid & 7; bplane = bs >> 2; bq = bs & 3; }
    int bcg = bcol;
    if (bmode) bcg = ((bcol >> 3) * 16) + bhalf * 8 + (bcol & 7);

    uint4 rah0, rah1, ral0, ral1, rb0, rb1, rb2, rb3;

    auto LOADF = [&](int tile) {
        const u16* pAh = Ah0; const u16* pAl = Al0; int kk = tile * 64;
        if (tile >= phsw) { pAh = Ah1; pAl = Al1; kk = (tile - phsw) * 64; }
        const u16* pa = pAh + (size_t)srow * 1024 + kk + skE;
        rah0 = *(const uint4*)(pa);
        rah1 = *(const uint4*)(pa + 8);
        const u16* pl = pAl + (size_t)srow * 1024 + kk + skE;
        ral0 = *(const uint4*)(pl);
        ral1 = *(const uint4*)(pl + 8);
        const u16* bp = bplane ? Bl : Bh;
        if constexpr (NC == 64) {
            const u16* s = bp + (size_t)bcg * ldb + tile * 64 + bq * 32;
            rb0 = *(const uint4*)(s);
            rb1 = *(const uint4*)(s + 8);
            rb2 = *(const uint4*)(s + 16);
            rb3 = *(const uint4*)(s + 24);
        } else {
            const u16* s = bp + (size_t)bcg * ldb + tile * 64 + bq * 16;
            rb0 = *(const uint4*)(s);
            rb1 = *(const uint4*)(s + 8);
        }
    };
    auto WRITEF = [&](int tile) {
        char* buf = smem + (tile & 1) * BUFB;
        char* d = buf + srow * ROWB + skE * 2;
        *(uint4*)d = rah0;
        *(uint4*)(d + 16) = rah1;
        *(uint4*)(d + APL2) = ral0;
        *(uint4*)(d + APL2 + 16) = ral1;
        char* e = buf + 2 * APL2 + bplane * BPL + bcol * ROWB;
        if constexpr (NC == 64) {
            char* p = e + bq * 64;
            *(uint4*)(p) = rb0; *(uint4*)(p + 16) = rb1;
            *(uint4*)(p + 32) = rb2; *(uint4*)(p + 48) = rb3;
        } else {
            char* p = e + bq * 32;
            *(uint4*)(p) = rb0; *(uint4*)(p + 16) = rb1;
        }
    };
    auto COMPUTEF = [&](int kt) {
        const char* buf = smem + (kt & 1) * BUFB;
        #pragma unroll
        for (int ks = 0; ks < 2; ++ks) {
            short8v ah[2], al[2], bh[NC/32], bl[NC/32];
            #pragma unroll
            for (int rfi = 0; rfi < 2; ++rfi) {
                int row = wrg * 32 + rfi * 16 + rlo;
                const char* p = buf + row * ROWB + ks * 64 + khi * 16;
                ah[rfi] = *(const short8v*)p;
                al[rfi] = *(const short8v*)(p + APL2);
            }
            #pragma unroll
            for (int cfi = 0; cfi < NC/32; ++cfi) {
                int col = wcg * (NC/2) + cfi * 16 + rlo;
                const char* q = buf + 2 * APL2 + col * ROWB + ks * 64 + khi * 16;
                bh[cfi] = *(const short8v*)q;
                bl[cfi] = *(const short8v*)(q + BPL);
            }
            #pragma unroll
            for (int rfi = 0; rfi < 2; ++rfi)
                #pragma unroll
                for (int cfi = 0; cfi < NC/32; ++cfi) {
                    acc[rfi][cfi] = __builtin_amdgcn_mfma_f32_16x16x32_bf16(ah[rfi], bh[cfi], acc[rfi][cfi], 0, 0, 0);
                    acc[rfi][cfi] = __builtin_amdgcn_mfma_f32_16x16x32_bf16(ah[rfi], bl[cfi], acc[rfi][cfi], 0, 0, 0);
                    acc[rfi][cfi] = __builtin_amdgcn_mfma_f32_16x16x32_bf16(al[rfi], bh[cfi], acc[rfi][cfi], 0, 0, 0);
                }
        }
    };

    LOADF(0); WRITEF(0); __syncthreads();
    for (int kt = 0; kt < nkt; ++kt) {
        if (kt + 1 < nkt) LOADF(kt + 1);
        COMPUTEF(kt);
        if (kt + 1 < nkt) WRITEF(kt + 1);
        __syncthreads();
    }
}

__global__ __launch_bounds__(256) void k_head1(const u16* __restrict__ ringh, const u16* __restrict__ ringl,
                                               const u16* __restrict__ Wh, const u16* __restrict__ Wl,
                                               const float* __restrict__ bias,
                                               u16* __restrict__ hsh, u16* __restrict__ hsl) {
    extern __shared__ char smem[];
    const int tid = threadIdx.x;
    const int nb = blockIdx.x, mb = blockIdx.y;
    const size_t m0 = (size_t)mb * 64;
    f32x4 acc[2][2];
    #pragma unroll
    for (int i = 0; i < 2; ++i) { acc[i][0] = (f32x4)0.f; acc[i][1] = (f32x4)0.f; }
    const u16* Ah = ringh + m0 * 1024;
    const u16* Al = ringl + m0 * 1024;
    gemm_core<64,0>(smem, tid, Ah, Al, Ah, Al, 99, nullptr,
                    Wh + (size_t)nb*64*1024, Wl + (size_t)nb*64*1024, 1024,
                    0, 0, 16, acc);
    const int lane = tid & 63, wid = tid >> 6;
    const int wrg = wid >> 1, wcg = wid & 1;
    const int rlo = lane & 15, khi = lane >> 4;
    #pragma unroll
    for (int rfi = 0; rfi < 2; ++rfi)
        #pragma unroll
        for (int cfi = 0; cfi < 2; ++cfi)
            #pragma unroll
            for (int r = 0; r < 4; ++r) {
                int row = wrg*32 + rfi*16 + khi*4 + r;
                int col = nb*64 + wcg*32 + cfi*16 + rlo;
                float v = acc[rfi][cfi][r] + bias[col];
                v = fmaxf(v, 0.f);
                u16 hh, hl; splitbf(v, hh, hl);
                size_t o = (m0 + row) * 1024 + col;
                hsh[o] = hh; hsl[o] = hl;
            }
}

__global__ __launch_bounds__(256) void k_head2(const u16* __restrict__ hsh, const u16* __restrict__ hsl,
                                               const u16* __restrict__ Wh, const u16* __restrict__ Wl,
                                               const float* __restrict__ bias,
                                               float* __restrict__ outp) {
    extern __shared__ char smem[];
    const int tid = threadIdx.x;
    const int nb = blockIdx.x, mb = blockIdx.y;
    const size_t m0 = (size_t)mb * 64;
    f32x4 acc[2][2];
    #pragma unroll
    for (int i = 0; i < 2; ++i) { acc[i][0] = (f32x4)0.f; acc[i][1] = (f32x4)0.f; }
    const u16* Ah = hsh + m0 * 1024;
    const u16* Al = hsl + m0 * 1024;
    gemm_core<64,0>(smem, tid, Ah, Al, Ah, Al, 99, nullptr,
                    Wh + (size_t)nb*64*1024, Wl + (size_t)nb*64*1024, 1024,
                    0, 0, 16, acc);
    const int lane = tid & 63, wid = tid >> 6;
    const int wrg = wid >> 1, wcg = wid & 1;
    const int rlo = lane & 15, khi = lane >> 4;
    #pragma unroll
    for (int rfi = 0; rfi < 2; ++rfi)
        #pragma unroll
        for (int cfi = 0; cfi < 2; ++cfi)
            #pragma unroll
            for (int r = 0; r < 4; ++r) {
                int row = wrg*32 + rfi*16 + khi*4 + r;
                int col = nb*64 + wcg*32 + cfi*16 + rlo;
                outp[(m0 + row) * 256 + col] = acc[rfi][cfi][r] + bias[col];
            }
}

// ---------------- host ----------------
extern "C" void kernel_launch(void* const* d_in, const int* in_sizes, int n_in,
                              void* d_out, int out_size, void* d_ws, size_t ws_size,
                              hipStream_t stream)
{
    (void)in_sizes; (void)n_in; (void)out_size;
    const float* inputs = (const float*)d_in[0];
    const float* embW   = (const float*)d_in[1];
    const float* W0     = (const float*)d_in[2];
    const float* b0     = (const float*)d_in[3];
    const float* W1     = (const float*)d_in[4];
    const float* b1     = (const float*)d_in[5];
    const float* oW0    = (const float*)d_in[6];
    const float* ob0    = (const float*)d_in[7];
    const float* oW1    = (const float*)d_in[8];
    const float* ob1    = (const float*)d_in[9];
    float* out = (float*)d_out;

    char* base = (char*)d_ws;
    size_t off = 0;
    auto take = [&](size_t n) -> char* {
        size_t a = (off + 255) & ~(size_t)255;
        char* r = base + a;
        off = a + n;
        return r;
    };

    u16* WFh = (u16*)take(4096ull * KPWF * 2);
    u16* WFl = (u16*)take(4096ull * KPWF * 2);
    u16* W0h = (u16*)take(4096ull * 1024 * 2);
    u16* W0l = (u16*)take(4096ull * 1024 * 2);
    u16* W1h = (u16*)take(4096ull * 2048 * 2);
    u16* W1l = (u16*)take(4096ull * 2048 * 2);
    u16* oWAh = (u16*)take(1024ull * 1024 * 2);
    u16* oWAl = (u16*)take(1024ull * 1024 * 2);
    u16* oWBh = (u16*)take(256ull * 1024 * 2);
    u16* oWBl = (u16*)take(256ull * 1024 * 2);
    float* WFfold = (float*)take(259ull * 4096 * 4);
    float* Sv = (float*)take(4096 * 4);
    float* SG = (float*)take((size_t)TT * BB * 4);
    float* Zin = (float*)take(2ull * BB * 4096 * 4);
    float* P0  = (float*)take(2ull * BB * 4096 * 4);
    float* P1  = (float*)take(4ull * BB * 4096 * 4);
    u16* h0h0 = (u16*)take((size_t)BB * 1024 * 2);
    u16* h0l0 = (u16*)take((size_t)BB * 1024 * 2);
    u16* h0h1 = (u16*)take((size_t)BB * 1024 * 2);
    u16* h0l1 = (u16*)take((size_t)BB * 1024 * 2);
    float* c0 = (float*)take((size_t)BB * 1024 * 4);
    float* c1 = (float*)take((size_t)BB * 1024 * 4);

    size_t avail = (ws_size > off + (1u << 20)) ? (ws_size - off - (1u << 20)) : 0;
    int R = 512;
    while (R > 2 && (size_t)R * (BB * 1024ull * 2 * 4) > avail) R >>= 1;
    u16* ringh = (u16*)take((size_t)R * BB * 1024 * 2);
    u16* ringl = (u16*)take((size_t)R * BB * 1024 * 2);
    u16* hsh   = (u16*)take((size_t)R * BB * 1024 * 2);
    u16* hsl   = (u16*)take((size_t)R * BB * 1024 * 2);

    // -------- prep --------
    k_fold<<<dim3(16, 259), 256, 0, stream>>>(embW, W0, WFfold);
    k_S<<<16, 256, 0, stream>>>(W0, Sv);
    k_sgn<<<256, 256, 0, stream>>>(inputs, SG);
    k_split<<<dim3(2, 4096), 256, 0, stream>>>(WFfold, 4096, 259, KPWF, 1, WFh, WFl);
    k_split<<<dim3(4, 4096), 256, 0, stream>>>(W0 + 640ull * 4096, 4096, 1024, 1024, 1, W0h, W0l);
    k_split<<<dim3(8, 4096), 256, 0, stream>>>(W1, 4096, 2048, 2048, 1, W1h, W1l);
    k_split<<<dim3(4, 1024), 256, 0, stream>>>(oW0, 1024, 1024, 1024, 0, oWAh, oWAl);
    k_split<<<dim3(4, 256), 256, 0, stream>>>(oW1, 256, 1024, 1024, 0, oWBh, oWBl);
    k_zero<<<64, 256, 0, stream>>>(c0, BB * 1024);
    k_zero<<<64, 256, 0, stream>>>(c1, BB * 1024);
    k_zero<<<32, 256, 0, stream>>>((float*)h0h1, BB * 1024 / 2);
    k_zero<<<32, 256, 0, stream>>>((float*)h0l1, BB * 1024 / 2);
    k_zero<<<32, 256, 0, stream>>>((float*)(ringh + (size_t)(R - 1) * BB * 1024), BB * 1024 / 2);
    k_zero<<<32, 256, 0, stream>>>((float*)(ringl + (size_t)(R - 1) * BB * 1024), BB * 1024 / 2);

    // -------- serial recurrence: A=GEMM partials, B=combine+gates --------
    GArgs ga;
    ga.inp = inputs;
    ga.WFh = WFh; ga.WFl = WFl; ga.W0h = W0h; ga.W0l = W0l; ga.W1h = W1h; ga.W1l = W1l;
    ga.h0h0 = h0h0; ga.h0l0 = h0l0; ga.h0h1 = h0h1; ga.h0l1 = h0l1;
    ga.ringh = ringh; ga.ringl = ringl;
    ga.P0 = P0; ga.P1 = P1; ga.Zin = Zin;
    ga.R = R;

    TArgs ta;
    ta.P0 = P0; ta.P1 = P1; ta.Zin = Zin; ta.Sv = Sv; ta.SG = SG; ta.b0 = b0; ta.b1 = b1;
    ta.c0 = c0; ta.c1 = c1;
    ta.h0h0 = h0h0; ta.h0l0 = h0l0; ta.h0h1 = h0h1; ta.h0l1 = h0l1;
    ta.ringh = ringh; ta.ringl = ringl;
    ta.R = R;

    for (int L = -1; L <= TT; ++L) {
        ga.t = L;
        k_gemm<<<224, 256, LDS_G, stream>>>(ga);
        ta.t = L;
        k_gate<<<64, 256, 0, stream>>>(ta);
        if (L >= R && (L % R) == 0) {
            int c = L / R - 1;
            k_head1<<<dim3(16, R * 2), 256, LDS_H, stream>>>(ringh, ringl, oWAh, oWAl, ob0, hsh, hsl);
            k_head2<<<dim3(4, R * 2), 256, LDS_H, stream>>>(hsh, hsl, oWBh, oWBl, ob1,
                                                            out + (size_t)c * R * BB * 256);
        }
    }
}